// Round 1
// baseline (101.861 us; speedup 1.0000x reference)
//
#include <hip/hip_runtime.h>

// Problem constants (match reference)
#define NB 8
#define HH 352
#define WW 352
#define RAD 5
#define TX 32
#define TY 32
#define LW (TX + 2*RAD)          // 42
#define LH (TY + 2*RAD)          // 42
#define SST 44                   // SoA plane row stride in floats; 44 mod 32 = 12 ->
                                 // 8 consecutive rows land in 8 distinct bank-quads (b128 conflict-free)
#define PLANE (LH * SST)         // 1848 floats = 7392 B (16B aligned multiple)
#define TILES_X (WW / TX)        // 11
#define TILES_Y (HH / TY)        // 11
#define NBLK (TILES_X * TILES_Y * NB)  // 968

// Pre-scale rgb by sqrt(ALPHA * log2(e)) so wgt = exp2(-sum(d^2))
#define RGB_SCALE 16.98644781888824f

typedef float f32x2 __attribute__((ext_vector_type(2)));

__device__ __forceinline__ f32x2 lo2(float4 q) { f32x2 r; r.x = q.x; r.y = q.y; return r; }
__device__ __forceinline__ f32x2 hi2(float4 q) { f32x2 r; r.x = q.z; r.y = q.w; return r; }
__device__ __forceinline__ f32x2 splat2(float v) { f32x2 r; r.x = v; r.y = v; return r; }
__device__ __forceinline__ float elem(float4 q, int c) {
    return c == 0 ? q.x : c == 1 ? q.y : c == 2 ? q.z : q.w;
}

// Separable-ish 5x5 dil-ero mask for 4 x-adjacent pixels (reads SoA sal plane).
template <bool INTERIOR>
__device__ __forceinline__ void compute_mask4(const float* __restrict__ sms,
                                              int ty, int px0, int gy, int gx0,
                                              float* mask) {
    float cmx[8], cmn[8];
    #pragma unroll
    for (int j = 0; j < 8; ++j) {
        int col = px0 + 3 + j;   // tile x of (gx0 - 2 + j)
        float mx = 0.f, mn = 1.f;
        #pragma unroll
        for (int r = 0; r < 5; ++r) {
            float l = (sms[(ty + 3 + r) * SST + col] > 0.5f) ? 1.f : 0.f;
            mx = fmaxf(mx, l);
            if (INTERIOR) {
                mn = fminf(mn, l);
            } else {
                bool rowv = (unsigned)(gy - 2 + r) < (unsigned)HH;
                mn = fminf(mn, rowv ? l : 1.f);
            }
        }
        cmx[j] = mx;
        if (INTERIOR) {
            cmn[j] = mn;
        } else {
            bool colv = (unsigned)(gx0 - 2 + j) < (unsigned)WW;
            cmn[j] = colv ? mn : 1.f;
        }
    }
    #pragma unroll
    for (int k = 0; k < 4; ++k) {
        float mx = cmx[k], mn = cmn[k];
        #pragma unroll
        for (int j2 = 1; j2 < 5; ++j2) {
            mx = fmaxf(mx, cmx[k + j2]);
            mn = fminf(mn, cmn[k + j2]);
        }
        mask[k] = mx - mn;  // 0 or 1
    }
}

__global__ __launch_bounds__(256, 4)
void btm_loss_kernel(const float* __restrict__ pred,
                     const float* __restrict__ feat,
                     float2* __restrict__ partials) {
    __shared__ __align__(16) float sm[4 * PLANE];   // 29.6 KB: SoA planes r,g,b,sal
    __shared__ float2 wred[4];

    float* const smr = sm;
    float* const smg = sm + PLANE;
    float* const smb = sm + 2 * PLANE;
    float* const sms = sm + 3 * PLANE;

    const int bid = blockIdx.x;
    const int tx_blk = bid % TILES_X;
    const int ty_blk = (bid / TILES_X) % TILES_Y;
    const int n = bid / (TILES_X * TILES_Y);
    const int x0 = tx_blk * TX;
    const int y0 = ty_blk * TY;

    const size_t plane = (size_t)HH * WW;
    const float* fr = feat + ((size_t)n * 3 + 0) * plane;
    const float* fg = feat + ((size_t)n * 3 + 1) * plane;
    const float* fb = feat + ((size_t)n * 3 + 2) * plane;
    const float* ps = pred + (size_t)n * plane;

    // ---- stage tile SoA (zero-padded halo, matching jnp.pad; rgb pre-scaled) ----
    for (int i = threadIdx.x; i < LH * LW; i += 256) {
        int lr = i / LW;
        int lc = i - lr * LW;
        int gy = y0 + lr - RAD;
        int gx = x0 + lc - RAD;
        float r = 0.f, g = 0.f, b = 0.f, s = 0.f;
        if ((unsigned)gy < (unsigned)HH && (unsigned)gx < (unsigned)WW) {
            int gi = gy * WW + gx;
            r = fr[gi] * RGB_SCALE;
            g = fg[gi] * RGB_SCALE;
            b = fb[gi] * RGB_SCALE;
            s = ps[gi];
        }
        int o = lr * SST + lc;
        smr[o] = r; smg[o] = g; smb[o] = b; sms[o] = s;
    }
    __syncthreads();

    // Each thread owns 4 x-adjacent pixels; 256 threads cover the full 32x32 tile.
    const int t   = threadIdx.x;
    const int txq = t & 7;       // 0..7
    const int ty  = t >> 3;      // 0..31
    const int px0 = txq * 4;

    // Pre-NEGATED center splats: d = w + (-c) == w - c bit-exactly, and maps to
    // plain v_pk_add_f32 (no modifiers, no per-tap splat movs).
    f32x2 ncr[4], ncg[4], ncb[4], ncs[4];
    {
        const int cb = (ty + RAD) * SST + px0 + RAD;
        #pragma unroll
        for (int i = 0; i < 4; ++i) {
            ncr[i] = splat2(-smr[cb + i]);
            ncg[i] = splat2(-smg[cb + i]);
            ncb[i] = splat2(-smb[cb + i]);
            ncs[i] = splat2(-sms[cb + i]);
        }
    }

    float accA[4] = {0.f, 0.f, 0.f, 0.f};
    float accB[4] = {0.f, 0.f, 0.f, 0.f};

    int ro = ty * SST + px0;
    for (int dy = 0; dy < 2 * RAD + 1; ++dy, ro += SST) {
        // 16 floats per component (need cols px0..px0+13) as 4 aligned b128 reads each.
        float4 Rq[4], Gq[4], Bq[4], Sq[4];
        #pragma unroll
        for (int q = 0; q < 4; ++q) {
            Rq[q] = *(const float4*)&smr[ro + 4 * q];
            Gq[q] = *(const float4*)&smg[ro + 4 * q];
            Bq[q] = *(const float4*)&smb[ro + 4 * q];
            Sq[q] = *(const float4*)&sms[ro + 4 * q];
        }

        #pragma unroll
        for (int i = 0; i < 4; ++i) {
            // Pair taps: window-column pairs (k,k+1) at even k so each f32x2 is a
            // natural aligned subregister of the float4 loads.
            //  i even: pairs at d = 0,2,4,6,8  (+ scalar d=10)
            //  i odd : pairs at d = 1,3,5,7,9  (+ scalar d=0)
            const int bp = (i + 1) >> 1;
            #pragma unroll
            for (int j = 0; j < 5; ++j) {
                const int p = bp + j;            // pair index; k = 2p
                f32x2 wr = (p & 1) ? hi2(Rq[p >> 1]) : lo2(Rq[p >> 1]);
                f32x2 wg = (p & 1) ? hi2(Gq[p >> 1]) : lo2(Gq[p >> 1]);
                f32x2 wb = (p & 1) ? hi2(Bq[p >> 1]) : lo2(Bq[p >> 1]);
                f32x2 ws = (p & 1) ? hi2(Sq[p >> 1]) : lo2(Sq[p >> 1]);

                f32x2 d0 = wr + ncr[i];          // pk_add
                f32x2 ssum = d0 * d0;            // pk_mul
                f32x2 d1 = wg + ncg[i];
                ssum += d1 * d1;                 // pk_fma
                f32x2 d2 = wb + ncb[i];
                ssum += d2 * d2;                 // pk_fma
                f32x2 dsv = ws + ncs[i];         // pk_add

                accA[i] = fmaf(__builtin_amdgcn_exp2f(-ssum.x), fabsf(dsv.x), accA[i]);
                accB[i] = fmaf(__builtin_amdgcn_exp2f(-ssum.y), fabsf(dsv.y), accB[i]);
            }
            // Scalar edge tap (d=10 for even i, d=0 for odd i)
            {
                const int ks = (i & 1) ? i : (i + 10);
                const int q = ks >> 2, c = ks & 3;
                float d0 = elem(Rq[q], c) + ncr[i].x;
                float d1 = elem(Gq[q], c) + ncg[i].x;
                float d2 = elem(Bq[q], c) + ncb[i].x;
                float s2 = fmaf(d0, d0, fmaf(d1, d1, d2 * d2));
                accB[i] = fmaf(__builtin_amdgcn_exp2f(-s2),
                               fabsf(elem(Sq[q], c) + ncs[i].x), accB[i]);
            }
        }
    }

    // ---- mask + per-thread num/den ----
    const int gy  = y0 + ty;
    const int gx0 = x0 + px0;
    float mask[4];
    const bool interior = (tx_blk >= 1) && (tx_blk <= TILES_X - 2) &&
                          (ty_blk >= 1) && (ty_blk <= TILES_Y - 2);
    if (interior) compute_mask4<true >(sms, ty, px0, gy, gx0, mask);
    else          compute_mask4<false>(sms, ty, px0, gy, gx0, mask);

    float num = fmaf(mask[0], accA[0] + accB[0],
                fmaf(mask[1], accA[1] + accB[1],
                fmaf(mask[2], accA[2] + accB[2],
                     mask[3] * (accA[3] + accB[3]))));
    float den = (mask[0] + mask[1]) + (mask[2] + mask[3]);

    // ---- wave reduce -> block reduce -> deterministic partial store ----
    #pragma unroll
    for (int off = 32; off > 0; off >>= 1) {
        num += __shfl_down(num, off, 64);
        den += __shfl_down(den, off, 64);
    }
    const int wid  = t >> 6;
    const int lane = t & 63;
    if (lane == 0) wred[wid] = make_float2(num, den);
    __syncthreads();
    if (t == 0) {
        float2 a = wred[0];
        #pragma unroll
        for (int w = 1; w < 4; ++w) { a.x += wred[w].x; a.y += wred[w].y; }
        partials[bid] = a;
    }
}

__global__ __launch_bounds__(256)
void btm_finalize_kernel(const float2* __restrict__ partials,
                         float* __restrict__ out) {
    __shared__ float2 wred[4];
    float num = 0.f, den = 0.f;
    for (int i = threadIdx.x; i < NBLK; i += 256) {
        float2 p = partials[i];
        num += p.x;
        den += p.y;
    }
    #pragma unroll
    for (int off = 32; off > 0; off >>= 1) {
        num += __shfl_down(num, off, 64);
        den += __shfl_down(den, off, 64);
    }
    int wid  = threadIdx.x >> 6;
    int lane = threadIdx.x & 63;
    if (lane == 0) wred[wid] = make_float2(num, den);
    __syncthreads();
    if (threadIdx.x == 0) {
        float2 a = wred[0];
        #pragma unroll
        for (int w = 1; w < 4; ++w) { a.x += wred[w].x; a.y += wred[w].y; }
        out[0] = a.x / (a.y + 1e-6f);
    }
}

extern "C" void kernel_launch(void* const* d_in, const int* in_sizes, int n_in,
                              void* d_out, int out_size, void* d_ws, size_t ws_size,
                              hipStream_t stream) {
    const float* pred = (const float*)d_in[0];  // (8,1,352,352) fp32
    const float* feat = (const float*)d_in[1];  // (8,3,352,352) fp32
    float* out = (float*)d_out;                 // scalar fp32
    float2* partials = (float2*)d_ws;           // NBLK float2 = 7.7 KB

    btm_loss_kernel<<<dim3(NBLK), dim3(256), 0, stream>>>(pred, feat, partials);
    btm_finalize_kernel<<<dim3(1), dim3(256), 0, stream>>>(partials, out);
}